// Round 1
// baseline (843.266 us; speedup 1.0000x reference)
//
#include <hip/hip_runtime.h>
#include <hip/hip_bf16.h>

// Problem constants (ChainGraphDQN)
#define NN 200000      // nodes
#define FIN 128        // in features
#define NE 3200000     // edges
#define NG 4096        // graphs
#define HC 16          // GCN out channels
#define D1 64          // MLP hidden
#define NM 12          // heads
#define NA 8           // actions
#define NBLK 782       // ceil(NN/256)

// Bucketed edge layout: 128 dst-nodes per bucket, 8 XCD-split sub-lists each.
#define BSHIFT 7
#define NBUCK 1563                 // ceil(NN/128)
#define NSUB (NBUCK * 8)           // 12504
#define CAP 512                    // per sub-list; expected 256, sigma 16

// Scratch in module __device__ globals.
__device__ float    g_h[NN * HC];                 // 12.8 MB
__device__ unsigned g_bucket[(size_t)NSUB * CAP]; // 25.6 MB
__device__ int      g_scnt[NSUB];
__device__ int      g_degi[NN];
__device__ float    g_dinv[NN];
__device__ float    g_pooled[NG * HC];
__device__ float    g_cnt[NG];

__device__ __forceinline__ void atomAddF(float* p, float v) {
    unsafeAtomicAdd(p, v);
}

// ---------------- zero the accumulators -------------------------------------
__global__ __launch_bounds__(256) void k_zero() {
    int i = blockIdx.x * 256 + threadIdx.x;
    if (i < NN) g_degi[i] = 0;
    if (i < NSUB) g_scnt[i] = 0;
    if (i < NG * HC) g_pooled[i] = 0.f;
    if (i < NG) g_cnt[i] = 0.f;
}

// ---------------- h = x @ conv_w (LDS-tiled, coalesced) ---------------------
// 64 rows/block; x-tile staged in LDS (stride 132 kills 16-way bank conflict).
__global__ __launch_bounds__(256) void k_xw(const float* __restrict__ x,
                                            const float* __restrict__ conv_w) {
    __shared__ float s_w[FIN * HC];      // 8 KB
    __shared__ float s_x[64 * 132];      // 33.8 KB
    int t = threadIdx.x;
    for (int i = t; i < FIN * HC; i += 256) s_w[i] = conv_w[i];
    int base = blockIdx.x * 64;
    for (int idx = t; idx < 64 * FIN; idx += 256) {
        int r = idx >> 7, k = idx & 127;
        s_x[r * 132 + k] = x[(size_t)(base + r) * FIN + k];
    }
    __syncthreads();
    int c = t & 15, rg = t >> 4;         // rg in 0..15; rows rg+16q
    float acc[4] = {0.f, 0.f, 0.f, 0.f};
    for (int k = 0; k < FIN; k++) {
        float w = s_w[k * HC + c];
#pragma unroll
        for (int q = 0; q < 4; q++)
            acc[q] = fmaf(s_x[(rg + 16 * q) * 132 + k], w, acc[q]);
    }
#pragma unroll
    for (int q = 0; q < 4; q++)
        g_h[(size_t)(base + rg + 16 * q) * HC + c] = acc[q];
}

// ---------------- bucket edges by dst (fused degree count) ------------------
// Sub-list chosen by blockIdx&7 so appends to one sub-list come (mostly) from
// one XCD -> L2-coalesced sequential writes instead of random 8B scatter.
// Payload packs src (18 bits) and dst&127 (7 bits) into 4 bytes.
__global__ __launch_bounds__(256) void k_bucket(const int* __restrict__ ei) {
    int e = blockIdx.x * 256 + threadIdx.x;
    if (e >= NE) return;
    int s = ei[e], d = ei[NE + e];
    atomicAdd(&g_degi[d], 1);
    int sub = ((d >> BSHIFT) << 3) + (blockIdx.x & 7);
    int pos = atomicAdd(&g_scnt[sub], 1);
    if (pos < CAP)
        g_bucket[(size_t)sub * CAP + pos] =
            (unsigned)s | ((unsigned)(d & 127) << 18);
}

// ---------------- dinv = rsqrt(deg+1) ---------------------------------------
__global__ __launch_bounds__(256) void k_dinv() {
    int i = blockIdx.x * 256 + threadIdx.x;
    if (i < NN) g_dinv[i] = rsqrtf((float)(g_degi[i] + 1));
}

// ---------------- aggregate + relu + fused mean-pool ------------------------
// One workgroup per 128-node bucket. 16 lanes per edge gather h[src] (64B
// coalesced), scale by dinv[src], ds_add into LDS agg tile. Then self-loop,
// bias, relu, and LDS pre-aggregated mean-pool (batch sorted => slot<16).
__global__ __launch_bounds__(256) void k_agg(const float* __restrict__ conv_b,
                                             const int* __restrict__ batch) {
    __shared__ float s_agg[128 * HC];    // 8 KB
    __shared__ float s_pool[16 * 16];
    __shared__ int s_cnt16[16];
    __shared__ int s_len[8];
    __shared__ int s_b0;
    int t = threadIdx.x;
    int bk = blockIdx.x;
    int base = bk << BSHIFT;

    for (int i = t; i < 128 * HC; i += 256) s_agg[i] = 0.f;
    s_pool[t >= 256 ? 0 : t] = 0.f;      // t<256 always; keeps compiler honest
    if (t < 16) s_cnt16[t] = 0;
    if (t < 8) {
        int l = g_scnt[(bk << 3) + t];
        s_len[t] = l < CAP ? l : CAP;
    }
    if (t == 0) s_b0 = batch[base];
    __syncthreads();

    int e16 = t >> 4, c = t & 15;
    for (int k = 0; k < 8; k++) {
        int len = s_len[k];
        const unsigned* lst = g_bucket + ((size_t)((bk << 3) + k)) * CAP;
        for (int j = e16; j < len; j += 16) {
            unsigned p = lst[j];
            int s = (int)(p & 0x3FFFFu);
            int dl = (int)(p >> 18);
            float hv = g_h[(size_t)s * HC + c];
            float di = g_dinv[s];
            atomicAdd(&s_agg[dl * HC + c], hv * di);
        }
    }
    __syncthreads();

#pragma unroll
    for (int q = 0; q < 8; q++) {
        int ln = (t >> 4) + q * 16;      // local node 0..127
        int node = base + ln;
        if (node < NN) {
            float di = g_dinv[node];
            float val = di * (s_agg[ln * HC + c] +
                              g_h[(size_t)node * HC + c] * di) + conv_b[c];
            float r = val > 0.f ? val : 0.f;
            int b = batch[node];
            int slot = b - s_b0;
            if (slot < 16) {
                atomicAdd(&s_pool[slot * 16 + c], r);
                if (c == 0) atomicAdd(&s_cnt16[slot], 1);
            } else {                     // astronomically rare
                atomAddF(&g_pooled[(size_t)b * HC + c], r);
                if (c == 0) atomAddF(&g_cnt[b], 1.f);
            }
        }
    }
    __syncthreads();

    int slot2 = t >> 4;
    if (s_cnt16[slot2] > 0)
        atomAddF(&g_pooled[(size_t)(s_b0 + slot2) * HC + c], s_pool[t]);
    if (t < 16 && s_cnt16[t] > 0)
        atomAddF(&g_cnt[s_b0 + t], (float)s_cnt16[t]);
}

// ---------------- MLP + heads (f32 output) ----------------------------------
__global__ __launch_bounds__(256) void k_mlp(const float* __restrict__ w1,
                                             const float* __restrict__ b1,
                                             const float* __restrict__ w2,
                                             const float* __restrict__ b2,
                                             const float* __restrict__ head_w,
                                             const float* __restrict__ head_b,
                                             float* __restrict__ out) {
    __shared__ float s_w1[HC * D1];
    __shared__ float s_b1[D1];
    __shared__ float s_w2[D1 * D1];
    __shared__ float s_b2[D1];
    __shared__ float s_hw[NM * D1 * NA];
    __shared__ float s_hb[NM * NA];
    __shared__ float s_p[4][HC];
    __shared__ float s_g1[4][D1];
    __shared__ float s_g2[4][D1];

    int tid = threadIdx.x;
    for (int i = tid; i < HC * D1; i += 256) s_w1[i] = w1[i];
    for (int i = tid; i < D1; i += 256) { s_b1[i] = b1[i]; s_b2[i] = b2[i]; }
    for (int i = tid; i < D1 * D1; i += 256) s_w2[i] = w2[i];
    for (int i = tid; i < NM * D1 * NA; i += 256) s_hw[i] = head_w[i];
    for (int i = tid; i < NM * NA; i += 256) s_hb[i] = head_b[i];

    int grp = tid >> 6, lane = tid & 63;
    int g = blockIdx.x * 4 + grp;
    if (lane < HC) {
        float cc = g_cnt[g];
        s_p[grp][lane] = g_pooled[g * HC + lane] / fmaxf(cc, 1.0f);
    }
    __syncthreads();
    {
        float a = s_b1[lane];
#pragma unroll
        for (int c = 0; c < HC; c++) a = fmaf(s_p[grp][c], s_w1[c * D1 + lane], a);
        s_g1[grp][lane] = a > 0.f ? a : expm1f(a);
    }
    __syncthreads();
    {
        float a = s_b2[lane];
#pragma unroll
        for (int d = 0; d < D1; d++) a = fmaf(s_g1[grp][d], s_w2[d * D1 + lane], a);
        s_g2[grp][lane] = a > 0.f ? a : expm1f(a);
    }
    __syncthreads();
    for (int idx = lane; idx < NM * NA; idx += 64) {
        int m = idx >> 3, a = idx & 7;
        float v = s_hb[idx];
#pragma unroll
        for (int d = 0; d < D1; d++)
            v = fmaf(s_g2[grp][d], s_hw[m * (D1 * NA) + d * NA + a], v);
        out[(size_t)g * (NM * NA) + idx] = v;
    }
}

extern "C" void kernel_launch(void* const* d_in, const int* in_sizes, int n_in,
                              void* d_out, int out_size, void* d_ws, size_t ws_size,
                              hipStream_t stream) {
    const float* x      = (const float*)d_in[0];
    const int*   ei     = (const int*)d_in[1];
    const int*   batch  = (const int*)d_in[2];
    const float* conv_w = (const float*)d_in[3];
    const float* conv_b = (const float*)d_in[4];
    const float* w1     = (const float*)d_in[5];
    const float* b1     = (const float*)d_in[6];
    const float* w2     = (const float*)d_in[7];
    const float* b2     = (const float*)d_in[8];
    const float* head_w = (const float*)d_in[9];
    const float* head_b = (const float*)d_in[10];
    float* out = (float*)d_out;

    k_zero<<<NBLK, 256, 0, stream>>>();
    k_xw<<<NN / 64, 256, 0, stream>>>(x, conv_w);
    k_bucket<<<(NE + 255) / 256, 256, 0, stream>>>(ei);
    k_dinv<<<NBLK, 256, 0, stream>>>();
    k_agg<<<NBUCK, 256, 0, stream>>>(conv_b, batch);
    k_mlp<<<NG / 4, 256, 0, stream>>>(w1, b1, w2, b2, head_w, head_b, out);
}

// Round 2
// 811.880 us; speedup vs baseline: 1.0387x; 1.0387x over previous
//
#include <hip/hip_runtime.h>
#include <hip/hip_bf16.h>

// Problem constants (ChainGraphDQN)
#define NN 200000      // nodes
#define FIN 128        // in features
#define NE 3200000     // edges
#define NG 4096        // graphs
#define HC 16          // GCN out channels
#define D1 64          // MLP hidden
#define NM 12          // heads
#define NA 8           // actions
#define NBLK 782       // ceil(NN/256)

// Bucketed edge layout: 64 dst-nodes per bucket, 8 XCD-split sub-lists each.
#define BSHIFT 6
#define NBUCK 3125                 // NN/64 exactly
#define NSUB (NBUCK * 8)           // 25000
#define CAP 256                    // per sub-list; mean 128, sigma ~11

// Scratch in module __device__ globals.
__device__ float    g_h[NN * HC];                 // 12.8 MB, holds h*dinv
__device__ unsigned g_bucket[(size_t)NSUB * CAP]; // 25.6 MB
__device__ int      g_scnt[NSUB];
__device__ int      g_degi[NN];
__device__ float    g_dinv[NN];
__device__ float    g_pooled[NG * HC];
__device__ float    g_cnt[NG];

__device__ __forceinline__ void atomAddF(float* p, float v) {
    unsafeAtomicAdd(p, v);
}

// ---------------- zero the accumulators -------------------------------------
__global__ __launch_bounds__(256) void k_zero() {
    int i = blockIdx.x * 256 + threadIdx.x;
    if (i < NN) g_degi[i] = 0;
    if (i < NSUB) g_scnt[i] = 0;
    if (i < NG * HC) g_pooled[i] = 0.f;
    if (i < NG) g_cnt[i] = 0.f;
}

// ---------------- bucket edges by dst (fused degree count) ------------------
// Sub-list chosen by blockIdx&7 so appends to one sub-list come (mostly) from
// one XCD -> L2-coalesced sequential writes instead of random 8B scatter.
// Payload packs src (18 bits) and dst&63 (6 bits) into 4 bytes.
__global__ __launch_bounds__(256) void k_bucket(const int* __restrict__ ei) {
    int e = blockIdx.x * 256 + threadIdx.x;
    if (e >= NE) return;
    int s = ei[e], d = ei[NE + e];
    atomicAdd(&g_degi[d], 1);
    int sub = ((d >> BSHIFT) << 3) + (blockIdx.x & 7);
    int pos = atomicAdd(&g_scnt[sub], 1);
    if (pos < CAP)
        g_bucket[(size_t)sub * CAP + pos] =
            (unsigned)s | ((unsigned)(d & 63) << 18);
}

// ---------------- dinv = rsqrt(deg+1) ---------------------------------------
__global__ __launch_bounds__(256) void k_dinv() {
    int i = blockIdx.x * 256 + threadIdx.x;
    if (i < NN) g_dinv[i] = rsqrtf((float)(g_degi[i] + 1));
}

// ---------------- h' = (x @ conv_w) * dinv[row]  (LDS-tiled, coalesced) -----
// 64 rows/block; x-tile staged in LDS (stride 132 kills 16-way bank conflict).
// Pre-scaling by dinv[row] removes the per-edge dinv gather from k_agg.
__global__ __launch_bounds__(256) void k_xw(const float* __restrict__ x,
                                            const float* __restrict__ conv_w) {
    __shared__ float s_w[FIN * HC];      // 8 KB
    __shared__ float s_x[64 * 132];      // 33.8 KB
    int t = threadIdx.x;
    for (int i = t; i < FIN * HC; i += 256) s_w[i] = conv_w[i];
    int base = blockIdx.x * 64;
    for (int idx = t; idx < 64 * FIN; idx += 256) {
        int r = idx >> 7, k = idx & 127;
        s_x[r * 132 + k] = x[(size_t)(base + r) * FIN + k];
    }
    __syncthreads();
    int c = t & 15, rg = t >> 4;         // rg in 0..15; rows rg+16q
    float acc[4] = {0.f, 0.f, 0.f, 0.f};
    for (int k = 0; k < FIN; k++) {
        float w = s_w[k * HC + c];
#pragma unroll
        for (int q = 0; q < 4; q++)
            acc[q] = fmaf(s_x[(rg + 16 * q) * 132 + k], w, acc[q]);
    }
#pragma unroll
    for (int q = 0; q < 4; q++) {
        int row = base + rg + 16 * q;
        g_h[(size_t)row * HC + c] = acc[q] * g_dinv[row];
    }
}

// ---------------- aggregate + relu + fused mean-pool ------------------------
// One workgroup per 64-node bucket. 16 lanes per edge gather h'[src] (64B
// coalesced); uint4 packed-list loads give 4 independent gathers in flight
// per thread. LDS agg tile, then self-loop, bias, relu, LDS-pre-agg mean-pool.
__global__ __launch_bounds__(256) void k_agg(const float* __restrict__ conv_b,
                                             const int* __restrict__ batch) {
    __shared__ float s_agg[64 * HC];     // 4 KB
    __shared__ float s_pool[16 * 16];
    __shared__ int s_cnt16[16];
    __shared__ int s_len[8];
    __shared__ int s_b0;
    int t = threadIdx.x;
    int bk = blockIdx.x;
    int base = bk << BSHIFT;

    for (int i = t; i < 64 * HC; i += 256) s_agg[i] = 0.f;
    s_pool[t] = 0.f;
    if (t < 16) s_cnt16[t] = 0;
    if (t < 8) {
        int l = g_scnt[(bk << 3) + t];
        s_len[t] = l < CAP ? l : CAP;
    }
    if (t == 0) s_b0 = batch[base];
    __syncthreads();

    int e16 = t >> 4, c = t & 15;
    for (int k = 0; k < 8; k++) {
        int len = s_len[k];
        const unsigned* lst = g_bucket + ((size_t)((bk << 3) + k)) * CAP;
        const uint4* lst4 = (const uint4*)lst;
        int nv = len >> 2;
#pragma unroll 2
        for (int j = e16; j < nv; j += 16) {
            uint4 p = lst4[j];
            float h0 = g_h[(size_t)(p.x & 0x3FFFFu) * HC + c];
            float h1 = g_h[(size_t)(p.y & 0x3FFFFu) * HC + c];
            float h2 = g_h[(size_t)(p.z & 0x3FFFFu) * HC + c];
            float h3 = g_h[(size_t)(p.w & 0x3FFFFu) * HC + c];
            atomicAdd(&s_agg[(p.x >> 18) * HC + c], h0);
            atomicAdd(&s_agg[(p.y >> 18) * HC + c], h1);
            atomicAdd(&s_agg[(p.z >> 18) * HC + c], h2);
            atomicAdd(&s_agg[(p.w >> 18) * HC + c], h3);
        }
        for (int j = (nv << 2) + e16; j < len; j += 16) {
            unsigned p = lst[j];
            atomicAdd(&s_agg[(p >> 18) * HC + c],
                      g_h[(size_t)(p & 0x3FFFFu) * HC + c]);
        }
    }
    __syncthreads();

#pragma unroll
    for (int q = 0; q < 4; q++) {
        int ln = (t >> 4) + q * 16;      // local node 0..63
        int node = base + ln;            // NN = 3125*64 exactly, no bound check
        float di = g_dinv[node];
        // g_h holds h*dinv already: val = di*(sum + h'[node]) + bias
        float val = di * (s_agg[ln * HC + c] + g_h[(size_t)node * HC + c])
                    + conv_b[c];
        float r = val > 0.f ? val : 0.f;
        int b = batch[node];
        int slot = b - s_b0;
        if (slot < 16) {
            atomicAdd(&s_pool[slot * 16 + c], r);
            if (c == 0) atomicAdd(&s_cnt16[slot], 1);
        } else {                         // astronomically rare
            atomAddF(&g_pooled[(size_t)b * HC + c], r);
            if (c == 0) atomAddF(&g_cnt[b], 1.f);
        }
    }
    __syncthreads();

    int slot2 = t >> 4;
    if (s_cnt16[slot2] > 0)
        atomAddF(&g_pooled[(size_t)(s_b0 + slot2) * HC + c], s_pool[t]);
    if (t < 16 && s_cnt16[t] > 0)
        atomAddF(&g_cnt[s_b0 + t], (float)s_cnt16[t]);
}

// ---------------- MLP + heads (f32 output) ----------------------------------
__global__ __launch_bounds__(256) void k_mlp(const float* __restrict__ w1,
                                             const float* __restrict__ b1,
                                             const float* __restrict__ w2,
                                             const float* __restrict__ b2,
                                             const float* __restrict__ head_w,
                                             const float* __restrict__ head_b,
                                             float* __restrict__ out) {
    __shared__ float s_w1[HC * D1];
    __shared__ float s_b1[D1];
    __shared__ float s_w2[D1 * D1];
    __shared__ float s_b2[D1];
    __shared__ float s_hw[NM * D1 * NA];
    __shared__ float s_hb[NM * NA];
    __shared__ float s_p[4][HC];
    __shared__ float s_g1[4][D1];
    __shared__ float s_g2[4][D1];

    int tid = threadIdx.x;
    for (int i = tid; i < HC * D1; i += 256) s_w1[i] = w1[i];
    for (int i = tid; i < D1; i += 256) { s_b1[i] = b1[i]; s_b2[i] = b2[i]; }
    for (int i = tid; i < D1 * D1; i += 256) s_w2[i] = w2[i];
    for (int i = tid; i < NM * D1 * NA; i += 256) s_hw[i] = head_w[i];
    for (int i = tid; i < NM * NA; i += 256) s_hb[i] = head_b[i];

    int grp = tid >> 6, lane = tid & 63;
    int g = blockIdx.x * 4 + grp;
    if (lane < HC) {
        float cc = g_cnt[g];
        s_p[grp][lane] = g_pooled[g * HC + lane] / fmaxf(cc, 1.0f);
    }
    __syncthreads();
    {
        float a = s_b1[lane];
#pragma unroll
        for (int c = 0; c < HC; c++) a = fmaf(s_p[grp][c], s_w1[c * D1 + lane], a);
        s_g1[grp][lane] = a > 0.f ? a : expm1f(a);
    }
    __syncthreads();
    {
        float a = s_b2[lane];
#pragma unroll
        for (int d = 0; d < D1; d++) a = fmaf(s_g1[grp][d], s_w2[d * D1 + lane], a);
        s_g2[grp][lane] = a > 0.f ? a : expm1f(a);
    }
    __syncthreads();
    for (int idx = lane; idx < NM * NA; idx += 64) {
        int m = idx >> 3, a = idx & 7;
        float v = s_hb[idx];
#pragma unroll
        for (int d = 0; d < D1; d++)
            v = fmaf(s_g2[grp][d], s_hw[m * (D1 * NA) + d * NA + a], v);
        out[(size_t)g * (NM * NA) + idx] = v;
    }
}

extern "C" void kernel_launch(void* const* d_in, const int* in_sizes, int n_in,
                              void* d_out, int out_size, void* d_ws, size_t ws_size,
                              hipStream_t stream) {
    const float* x      = (const float*)d_in[0];
    const int*   ei     = (const int*)d_in[1];
    const int*   batch  = (const int*)d_in[2];
    const float* conv_w = (const float*)d_in[3];
    const float* conv_b = (const float*)d_in[4];
    const float* w1     = (const float*)d_in[5];
    const float* b1     = (const float*)d_in[6];
    const float* w2     = (const float*)d_in[7];
    const float* b2     = (const float*)d_in[8];
    const float* head_w = (const float*)d_in[9];
    const float* head_b = (const float*)d_in[10];
    float* out = (float*)d_out;

    k_zero<<<NBLK, 256, 0, stream>>>();
    k_bucket<<<(NE + 255) / 256, 256, 0, stream>>>(ei);
    k_dinv<<<NBLK, 256, 0, stream>>>();
    k_xw<<<NN / 64, 256, 0, stream>>>(x, conv_w);
    k_agg<<<NBUCK, 256, 0, stream>>>(conv_b, batch);
    k_mlp<<<NG / 4, 256, 0, stream>>>(w1, b1, w2, b2, head_w, head_b, out);
}

// Round 3
// 690.101 us; speedup vs baseline: 1.2219x; 1.1765x over previous
//
#include <hip/hip_runtime.h>
#include <hip/hip_bf16.h>

// Problem constants (ChainGraphDQN)
#define NN 200000      // nodes
#define FIN 128        // in features
#define NE 3200000     // edges
#define NG 4096        // graphs
#define HC 16          // GCN out channels
#define D1 64          // MLP hidden
#define NM 12          // heads
#define NA 8           // actions
#define NBLK 782       // ceil(NN/256)

// Binned edge layout: 64 dst-nodes per bin, one contiguous list per bin.
#define BSHIFT 6
#define NBIN 3125                  // NN/64 exactly
#define CAP 1536                   // per-bin capacity; mean 1024, sigma ~32
#define CH 16384                   // edges per binning block
#define NBBLK 196                  // ceil(NE/CH)

// Scratch in module __device__ globals.
__device__ float    g_h[NN * HC];                 // 12.8 MB, holds h*dinv
__device__ unsigned g_bucket[(size_t)NBIN * CAP]; // 19.2 MB
__device__ int      g_scnt[NBIN];
__device__ int      g_degi[NN];
__device__ float    g_dinv[NN];
__device__ float    g_pooled[NG * HC];
__device__ float    g_cnt[NG];

__device__ __forceinline__ void atomAddF(float* p, float v) {
    unsafeAtomicAdd(p, v);
}

// ---------------- zero the accumulators -------------------------------------
__global__ __launch_bounds__(256) void k_zero() {
    int i = blockIdx.x * 256 + threadIdx.x;
    if (i < NN) g_degi[i] = 0;
    if (i < NBIN) g_scnt[i] = 0;
    if (i < NG * HC) g_pooled[i] = 0.f;
    if (i < NG) g_cnt[i] = 0.f;
}

// ---------------- block-local counting sort into bins -----------------------
// Each block sorts CH contiguous edges by bin (dst>>6) in LDS, reserves one
// contiguous global fragment per (bin, block) via a single atomicAdd, then
// writes edges in sorted order: consecutive threads hit consecutive addresses
// within fragments => wave-coalesced, line-dense stores (the round-2 k_bucket
// wrote 64B per 4B store; this writes ~fragment-boundary slack only).
__global__ __launch_bounds__(1024) void k_bin(const int* __restrict__ ei) {
    __shared__ int            s_hist[NBIN];   // counts, reused as cursor
    __shared__ unsigned short s_pref[NBIN];   // block-local exclusive prefix
    __shared__ unsigned short s_gbase[NBIN];  // global fragment base
    __shared__ unsigned short s_perm[CH];     // sorted pos -> local edge idx
    __shared__ int            s_scan[1024];
    int t = threadIdx.x;
    int e0 = blockIdx.x * CH;
    int cnt = NE - e0; if (cnt > CH) cnt = CH;

    for (int b = t; b < NBIN; b += 1024) s_hist[b] = 0;
    __syncthreads();

    // pass A: histogram + fused degree count
    for (int i = t; i < cnt; i += 1024) {
        int d = ei[NE + e0 + i];
        atomicAdd(&g_degi[d], 1);
        atomicAdd(&s_hist[d >> BSHIFT], 1);
    }
    __syncthreads();

    // block scan over bins (4 bins/thread serial + 1024-wide Hillis-Steele)
    int b0 = t * 4;
    int lsum = 0;
#pragma unroll
    for (int k = 0; k < 4; k++) {
        int b = b0 + k;
        if (b < NBIN) lsum += s_hist[b];
    }
    s_scan[t] = lsum;
    __syncthreads();
    for (int o = 1; o < 1024; o <<= 1) {
        int u = (t >= o) ? s_scan[t - o] : 0;
        __syncthreads();
        s_scan[t] += u;
        __syncthreads();
    }
    int run = s_scan[t] - lsum;               // exclusive base for my bins
#pragma unroll
    for (int k = 0; k < 4; k++) {
        int b = b0 + k;
        if (b < NBIN) { s_pref[b] = (unsigned short)run; run += s_hist[b]; }
    }
    __syncthreads();

    // reserve global fragment space (one atomic per non-empty bin per block)
    for (int b = t; b < NBIN; b += 1024) {
        int c = s_hist[b];
        s_gbase[b] = (unsigned short)(c ? atomicAdd(&g_scnt[b], c) : 0);
    }
    __syncthreads();
    for (int b = t; b < NBIN; b += 1024) s_hist[b] = s_pref[b];  // cursor
    __syncthreads();

    // pass B: rank edges into sorted permutation
    for (int i = t; i < cnt; i += 1024) {
        int d = ei[NE + e0 + i];
        int pos = atomicAdd(&s_hist[d >> BSHIFT], 1);
        s_perm[pos] = (unsigned short)i;
    }
    __syncthreads();

    // pass C: write in sorted order (re-reads ei from L2-hot 128KB window)
#pragma unroll 4
    for (int i = t; i < cnt; i += 1024) {
        int idx = s_perm[i];
        int s = ei[e0 + idx];
        int d = ei[NE + e0 + idx];
        int bin = d >> BSHIFT;
        int gpos = s_gbase[bin] + (i - (int)s_pref[bin]);
        if (gpos < CAP)
            g_bucket[(size_t)bin * CAP + gpos] =
                (unsigned)s | ((unsigned)(d & 63) << 18);
    }
}

// ---------------- dinv = rsqrt(deg+1) ---------------------------------------
__global__ __launch_bounds__(256) void k_dinv() {
    int i = blockIdx.x * 256 + threadIdx.x;
    if (i < NN) g_dinv[i] = rsqrtf((float)(g_degi[i] + 1));
}

// ---------------- h' = (x @ conv_w) * dinv[row]  (LDS-tiled, coalesced) -----
// 64 rows/block; x-tile staged in LDS (stride 132 kills 16-way bank conflict).
// Pre-scaling by dinv[row] removes the per-edge dinv gather from k_agg.
__global__ __launch_bounds__(256) void k_xw(const float* __restrict__ x,
                                            const float* __restrict__ conv_w) {
    __shared__ float s_w[FIN * HC];      // 8 KB
    __shared__ float s_x[64 * 132];      // 33.8 KB
    int t = threadIdx.x;
    for (int i = t; i < FIN * HC; i += 256) s_w[i] = conv_w[i];
    int base = blockIdx.x * 64;
    for (int idx = t; idx < 64 * FIN; idx += 256) {
        int r = idx >> 7, k = idx & 127;
        s_x[r * 132 + k] = x[(size_t)(base + r) * FIN + k];
    }
    __syncthreads();
    int c = t & 15, rg = t >> 4;         // rg in 0..15; rows rg+16q
    float acc[4] = {0.f, 0.f, 0.f, 0.f};
    for (int k = 0; k < FIN; k++) {
        float w = s_w[k * HC + c];
#pragma unroll
        for (int q = 0; q < 4; q++)
            acc[q] = fmaf(s_x[(rg + 16 * q) * 132 + k], w, acc[q]);
    }
#pragma unroll
    for (int q = 0; q < 4; q++) {
        int row = base + rg + 16 * q;
        g_h[(size_t)row * HC + c] = acc[q] * g_dinv[row];
    }
}

// ---------------- aggregate + relu + fused mean-pool ------------------------
// One workgroup per 64-node bin; single contiguous edge list. 16 lanes per
// edge gather h'[src] (64B coalesced); uint4 packed-list loads give 4
// independent gathers in flight. LDS agg tile, then self-loop, bias, relu,
// LDS-pre-agg mean-pool (batch sorted => slot<16 with rare global fallback).
__global__ __launch_bounds__(256) void k_agg(const float* __restrict__ conv_b,
                                             const int* __restrict__ batch) {
    __shared__ float s_agg[64 * HC];     // 4 KB
    __shared__ float s_pool[16 * 16];
    __shared__ int s_cnt16[16];
    __shared__ int s_len;
    __shared__ int s_b0;
    int t = threadIdx.x;
    int bk = blockIdx.x;
    int base = bk << BSHIFT;

    for (int i = t; i < 64 * HC; i += 256) s_agg[i] = 0.f;
    s_pool[t] = 0.f;
    if (t < 16) s_cnt16[t] = 0;
    if (t == 0) {
        int l = g_scnt[bk];
        s_len = l < CAP ? l : CAP;
        s_b0 = batch[base];
    }
    __syncthreads();

    int e16 = t >> 4, c = t & 15;
    int len = s_len;
    const unsigned* lst = g_bucket + (size_t)bk * CAP;
    const uint4* lst4 = (const uint4*)lst;
    int nv = len >> 2;
#pragma unroll 2
    for (int j = e16; j < nv; j += 16) {
        uint4 p = lst4[j];
        float h0 = g_h[(size_t)(p.x & 0x3FFFFu) * HC + c];
        float h1 = g_h[(size_t)(p.y & 0x3FFFFu) * HC + c];
        float h2 = g_h[(size_t)(p.z & 0x3FFFFu) * HC + c];
        float h3 = g_h[(size_t)(p.w & 0x3FFFFu) * HC + c];
        atomicAdd(&s_agg[(p.x >> 18) * HC + c], h0);
        atomicAdd(&s_agg[(p.y >> 18) * HC + c], h1);
        atomicAdd(&s_agg[(p.z >> 18) * HC + c], h2);
        atomicAdd(&s_agg[(p.w >> 18) * HC + c], h3);
    }
    for (int j = (nv << 2) + e16; j < len; j += 16) {
        unsigned p = lst[j];
        atomicAdd(&s_agg[(p >> 18) * HC + c],
                  g_h[(size_t)(p & 0x3FFFFu) * HC + c]);
    }
    __syncthreads();

#pragma unroll
    for (int q = 0; q < 4; q++) {
        int ln = (t >> 4) + q * 16;      // local node 0..63
        int node = base + ln;            // NN = 3125*64 exactly, no bound check
        float di = g_dinv[node];
        // g_h holds h*dinv already: val = di*(sum + h'[node]) + bias
        float val = di * (s_agg[ln * HC + c] + g_h[(size_t)node * HC + c])
                    + conv_b[c];
        float r = val > 0.f ? val : 0.f;
        int b = batch[node];
        int slot = b - s_b0;
        if (slot < 16) {
            atomicAdd(&s_pool[slot * 16 + c], r);
            if (c == 0) atomicAdd(&s_cnt16[slot], 1);
        } else {                         // astronomically rare
            atomAddF(&g_pooled[(size_t)b * HC + c], r);
            if (c == 0) atomAddF(&g_cnt[b], 1.f);
        }
    }
    __syncthreads();

    int slot2 = t >> 4;
    if (s_cnt16[slot2] > 0)
        atomAddF(&g_pooled[(size_t)(s_b0 + slot2) * HC + c], s_pool[t]);
    if (t < 16 && s_cnt16[t] > 0)
        atomAddF(&g_cnt[s_b0 + t], (float)s_cnt16[t]);
}

// ---------------- MLP + heads (f32 output) ----------------------------------
__global__ __launch_bounds__(256) void k_mlp(const float* __restrict__ w1,
                                             const float* __restrict__ b1,
                                             const float* __restrict__ w2,
                                             const float* __restrict__ b2,
                                             const float* __restrict__ head_w,
                                             const float* __restrict__ head_b,
                                             float* __restrict__ out) {
    __shared__ float s_w1[HC * D1];
    __shared__ float s_b1[D1];
    __shared__ float s_w2[D1 * D1];
    __shared__ float s_b2[D1];
    __shared__ float s_hw[NM * D1 * NA];
    __shared__ float s_hb[NM * NA];
    __shared__ float s_p[4][HC];
    __shared__ float s_g1[4][D1];
    __shared__ float s_g2[4][D1];

    int tid = threadIdx.x;
    for (int i = tid; i < HC * D1; i += 256) s_w1[i] = w1[i];
    for (int i = tid; i < D1; i += 256) { s_b1[i] = b1[i]; s_b2[i] = b2[i]; }
    for (int i = tid; i < D1 * D1; i += 256) s_w2[i] = w2[i];
    for (int i = tid; i < NM * D1 * NA; i += 256) s_hw[i] = head_w[i];
    for (int i = tid; i < NM * NA; i += 256) s_hb[i] = head_b[i];

    int grp = tid >> 6, lane = tid & 63;
    int g = blockIdx.x * 4 + grp;
    if (lane < HC) {
        float cc = g_cnt[g];
        s_p[grp][lane] = g_pooled[g * HC + lane] / fmaxf(cc, 1.0f);
    }
    __syncthreads();
    {
        float a = s_b1[lane];
#pragma unroll
        for (int c = 0; c < HC; c++) a = fmaf(s_p[grp][c], s_w1[c * D1 + lane], a);
        s_g1[grp][lane] = a > 0.f ? a : expm1f(a);
    }
    __syncthreads();
    {
        float a = s_b2[lane];
#pragma unroll
        for (int d = 0; d < D1; d++) a = fmaf(s_g1[grp][d], s_w2[d * D1 + lane], a);
        s_g2[grp][lane] = a > 0.f ? a : expm1f(a);
    }
    __syncthreads();
    for (int idx = lane; idx < NM * NA; idx += 64) {
        int m = idx >> 3, a = idx & 7;
        float v = s_hb[idx];
#pragma unroll
        for (int d = 0; d < D1; d++)
            v = fmaf(s_g2[grp][d], s_hw[m * (D1 * NA) + d * NA + a], v);
        out[(size_t)g * (NM * NA) + idx] = v;
    }
}

extern "C" void kernel_launch(void* const* d_in, const int* in_sizes, int n_in,
                              void* d_out, int out_size, void* d_ws, size_t ws_size,
                              hipStream_t stream) {
    const float* x      = (const float*)d_in[0];
    const int*   ei     = (const int*)d_in[1];
    const int*   batch  = (const int*)d_in[2];
    const float* conv_w = (const float*)d_in[3];
    const float* conv_b = (const float*)d_in[4];
    const float* w1     = (const float*)d_in[5];
    const float* b1     = (const float*)d_in[6];
    const float* w2     = (const float*)d_in[7];
    const float* b2     = (const float*)d_in[8];
    const float* head_w = (const float*)d_in[9];
    const float* head_b = (const float*)d_in[10];
    float* out = (float*)d_out;

    k_zero<<<NBLK, 256, 0, stream>>>();
    k_bin<<<NBBLK, 1024, 0, stream>>>(ei);
    k_dinv<<<NBLK, 256, 0, stream>>>();
    k_xw<<<NN / 64, 256, 0, stream>>>(x, conv_w);
    k_agg<<<NBIN, 256, 0, stream>>>(conv_b, batch);
    k_mlp<<<NG / 4, 256, 0, stream>>>(w1, b1, w2, b2, head_w, head_b, out);
}

// Round 4
// 673.438 us; speedup vs baseline: 1.2522x; 1.0247x over previous
//
#include <hip/hip_runtime.h>
#include <hip/hip_bf16.h>

// Problem constants (ChainGraphDQN)
#define NN 200000      // nodes
#define FIN 128        // in features
#define NE 3200000     // edges
#define NG 4096        // graphs
#define HC 16          // GCN out channels
#define D1 64          // MLP hidden
#define NM 12          // heads
#define NA 8           // actions
#define NBLK 782       // ceil(NN/256)

// Binned edge layout: 64 dst-nodes per bin, one contiguous list per bin.
#define BSHIFT 6
#define NBIN 3125                  // NN/64 exactly
#define CAP 1536                   // per-bin capacity; mean 1024, sigma ~32
#define CH 8192                    // edges per binning block
#define NBBLK 391                  // ceil(NE/CH)

// Scratch in module __device__ globals.
__device__ float    g_h[NN * HC];                 // 12.8 MB, holds h*dinv
__device__ unsigned g_bucket[(size_t)NBIN * CAP]; // 19.2 MB
__device__ int      g_scnt[NBIN];
__device__ int      g_degi[NN];
__device__ float    g_dinv[NN];
__device__ float    g_pooled[NG * HC];
__device__ float    g_cnt[NG];

__device__ __forceinline__ void atomAddF(float* p, float v) {
    unsafeAtomicAdd(p, v);
}

// ---------------- zero the accumulators -------------------------------------
__global__ __launch_bounds__(256) void k_zero() {
    int i = blockIdx.x * 256 + threadIdx.x;
    if (i < NN) g_degi[i] = 0;
    if (i < NBIN) g_scnt[i] = 0;
    if (i < NG * HC) g_pooled[i] = 0.f;
    if (i < NG) g_cnt[i] = 0.f;
}

// ---------------- block-local counting sort into bins -----------------------
// Each block sorts CH contiguous edges by bin (dst>>6) in LDS, reserves one
// contiguous global fragment per (bin, block) via a single atomicAdd, then
// writes edges in sorted order => wave-coalesced, line-dense stores.
__global__ __launch_bounds__(1024) void k_bin(const int* __restrict__ ei) {
    __shared__ int            s_hist[NBIN];   // counts, reused as cursor
    __shared__ unsigned short s_pref[NBIN];   // block-local exclusive prefix
    __shared__ unsigned short s_gbase[NBIN];  // global fragment base
    __shared__ unsigned short s_perm[CH];     // sorted pos -> local edge idx
    __shared__ int            s_scan[1024];
    int t = threadIdx.x;
    int e0 = blockIdx.x * CH;
    int cnt = NE - e0; if (cnt > CH) cnt = CH;

    for (int b = t; b < NBIN; b += 1024) s_hist[b] = 0;
    __syncthreads();

    // pass A: histogram + fused degree count
    for (int i = t; i < cnt; i += 1024) {
        int d = ei[NE + e0 + i];
        atomicAdd(&g_degi[d], 1);
        atomicAdd(&s_hist[d >> BSHIFT], 1);
    }
    __syncthreads();

    // block scan over bins (4 bins/thread serial + 1024-wide Hillis-Steele)
    int b0 = t * 4;
    int lsum = 0;
#pragma unroll
    for (int k = 0; k < 4; k++) {
        int b = b0 + k;
        if (b < NBIN) lsum += s_hist[b];
    }
    s_scan[t] = lsum;
    __syncthreads();
    for (int o = 1; o < 1024; o <<= 1) {
        int u = (t >= o) ? s_scan[t - o] : 0;
        __syncthreads();
        s_scan[t] += u;
        __syncthreads();
    }
    int run = s_scan[t] - lsum;               // exclusive base for my bins
#pragma unroll
    for (int k = 0; k < 4; k++) {
        int b = b0 + k;
        if (b < NBIN) { s_pref[b] = (unsigned short)run; run += s_hist[b]; }
    }
    __syncthreads();

    // reserve global fragment space (one atomic per non-empty bin per block)
    for (int b = t; b < NBIN; b += 1024) {
        int c = s_hist[b];
        s_gbase[b] = (unsigned short)(c ? atomicAdd(&g_scnt[b], c) : 0);
    }
    __syncthreads();
    for (int b = t; b < NBIN; b += 1024) s_hist[b] = s_pref[b];  // cursor
    __syncthreads();

    // pass B: rank edges into sorted permutation
    for (int i = t; i < cnt; i += 1024) {
        int d = ei[NE + e0 + i];
        int pos = atomicAdd(&s_hist[d >> BSHIFT], 1);
        s_perm[pos] = (unsigned short)i;
    }
    __syncthreads();

    // pass C: write in sorted order (re-reads ei from L2-hot window)
#pragma unroll 4
    for (int i = t; i < cnt; i += 1024) {
        int idx = s_perm[i];
        int s = ei[e0 + idx];
        int d = ei[NE + e0 + idx];
        int bin = d >> BSHIFT;
        int gpos = s_gbase[bin] + (i - (int)s_pref[bin]);
        if (gpos < CAP)
            g_bucket[(size_t)bin * CAP + gpos] =
                (unsigned)s | ((unsigned)(d & 63) << 18);
    }
}

// ---------------- dinv = rsqrt(deg+1) ---------------------------------------
__global__ __launch_bounds__(256) void k_dinv() {
    int i = blockIdx.x * 256 + threadIdx.x;
    if (i < NN) g_dinv[i] = rsqrtf((float)(g_degi[i] + 1));
}

// ---------------- h' = (x @ conv_w) * dinv[row]  (LDS-tiled, coalesced) -----
__global__ __launch_bounds__(256) void k_xw(const float* __restrict__ x,
                                            const float* __restrict__ conv_w) {
    __shared__ float s_w[FIN * HC];      // 8 KB
    __shared__ float s_x[64 * 132];      // 33.8 KB
    int t = threadIdx.x;
    for (int i = t; i < FIN * HC; i += 256) s_w[i] = conv_w[i];
    int base = blockIdx.x * 64;
    for (int idx = t; idx < 64 * FIN; idx += 256) {
        int r = idx >> 7, k = idx & 127;
        s_x[r * 132 + k] = x[(size_t)(base + r) * FIN + k];
    }
    __syncthreads();
    int c = t & 15, rg = t >> 4;         // rg in 0..15; rows rg+16q
    float acc[4] = {0.f, 0.f, 0.f, 0.f};
    for (int k = 0; k < FIN; k++) {
        float w = s_w[k * HC + c];
#pragma unroll
        for (int q = 0; q < 4; q++)
            acc[q] = fmaf(s_x[(rg + 16 * q) * 132 + k], w, acc[q]);
    }
#pragma unroll
    for (int q = 0; q < 4; q++) {
        int row = base + rg + 16 * q;
        g_h[(size_t)row * HC + c] = acc[q] * g_dinv[row];
    }
}

// ---------------- aggregate + relu + fused mean-pool ------------------------
// One workgroup per 64-node bin. Edge list staged to LDS so the vmcnt queue
// holds ONLY h'-gathers. 4 lanes per edge, float4 each (quad covers the 64B
// row); 8-edge chunks issue 8 independent gathers before any LDS atomic =>
// ~128 lines in flight per wave (vs ~32 before). Then self-loop, bias, relu,
// LDS-pre-agg mean-pool (batch sorted => slot<16, rare global fallback).
__global__ __launch_bounds__(256) void k_agg(const float* __restrict__ conv_b,
                                             const int* __restrict__ batch) {
    __shared__ float s_agg[64 * HC];     // 4 KB
    __shared__ unsigned s_lst[CAP];      // 6 KB
    __shared__ float s_pool[16 * 16];
    __shared__ int s_cnt16[16];
    __shared__ int s_len;
    __shared__ int s_b0;
    int t = threadIdx.x;
    int bk = blockIdx.x;
    int base = bk << BSHIFT;

    for (int i = t; i < 64 * HC; i += 256) s_agg[i] = 0.f;
    s_pool[t] = 0.f;
    if (t < 16) s_cnt16[t] = 0;
    if (t == 0) {
        int l = g_scnt[bk];
        s_len = l < CAP ? l : CAP;
        s_b0 = batch[base];
    }
    __syncthreads();

    int len = s_len;
    const unsigned* lst = g_bucket + (size_t)bk * CAP;
    for (int i = t; i < len; i += 256) s_lst[i] = lst[i];
    __syncthreads();

    int q = t >> 2, cq = t & 3;          // 64 quads, lane cq owns floats 4cq..
    int jb = 0;
    for (; jb + 512 <= len; jb += 512) { // 8 edges per quad per chunk
        unsigned p[8];
        float4 hv[8];
#pragma unroll
        for (int k = 0; k < 8; k++) p[k] = s_lst[jb + q + 64 * k];
#pragma unroll
        for (int k = 0; k < 8; k++)
            hv[k] = *(const float4*)&g_h[(size_t)(p[k] & 0x3FFFFu) * HC + 4 * cq];
#pragma unroll
        for (int k = 0; k < 8; k++) {
            float* dp = &s_agg[(p[k] >> 18) * HC + 4 * cq];
            atomicAdd(dp + 0, hv[k].x);
            atomicAdd(dp + 1, hv[k].y);
            atomicAdd(dp + 2, hv[k].z);
            atomicAdd(dp + 3, hv[k].w);
        }
    }
    for (int j = jb + q; j < len; j += 64) {   // remainder
        unsigned p = s_lst[j];
        float4 hv = *(const float4*)&g_h[(size_t)(p & 0x3FFFFu) * HC + 4 * cq];
        float* dp = &s_agg[(p >> 18) * HC + 4 * cq];
        atomicAdd(dp + 0, hv.x);
        atomicAdd(dp + 1, hv.y);
        atomicAdd(dp + 2, hv.z);
        atomicAdd(dp + 3, hv.w);
    }
    __syncthreads();

    int c = t & 15;
#pragma unroll
    for (int qq = 0; qq < 4; qq++) {
        int ln = (t >> 4) + qq * 16;     // local node 0..63
        int node = base + ln;            // NN = 3125*64 exactly, no bound check
        float di = g_dinv[node];
        // g_h holds h*dinv already: val = di*(sum + h'[node]) + bias
        float val = di * (s_agg[ln * HC + c] + g_h[(size_t)node * HC + c])
                    + conv_b[c];
        float r = val > 0.f ? val : 0.f;
        int b = batch[node];
        int slot = b - s_b0;
        if (slot < 16) {
            atomicAdd(&s_pool[slot * 16 + c], r);
            if (c == 0) atomicAdd(&s_cnt16[slot], 1);
        } else {                         // astronomically rare
            atomAddF(&g_pooled[(size_t)b * HC + c], r);
            if (c == 0) atomAddF(&g_cnt[b], 1.f);
        }
    }
    __syncthreads();

    int slot2 = t >> 4;
    if (s_cnt16[slot2] > 0)
        atomAddF(&g_pooled[(size_t)(s_b0 + slot2) * HC + c], s_pool[t]);
    if (t < 16 && s_cnt16[t] > 0)
        atomAddF(&g_cnt[s_b0 + t], (float)s_cnt16[t]);
}

// ---------------- MLP + heads (f32 output) ----------------------------------
__global__ __launch_bounds__(256) void k_mlp(const float* __restrict__ w1,
                                             const float* __restrict__ b1,
                                             const float* __restrict__ w2,
                                             const float* __restrict__ b2,
                                             const float* __restrict__ head_w,
                                             const float* __restrict__ head_b,
                                             float* __restrict__ out) {
    __shared__ float s_w1[HC * D1];
    __shared__ float s_b1[D1];
    __shared__ float s_w2[D1 * D1];
    __shared__ float s_b2[D1];
    __shared__ float s_hw[NM * D1 * NA];
    __shared__ float s_hb[NM * NA];
    __shared__ float s_p[4][HC];
    __shared__ float s_g1[4][D1];
    __shared__ float s_g2[4][D1];

    int tid = threadIdx.x;
    for (int i = tid; i < HC * D1; i += 256) s_w1[i] = w1[i];
    for (int i = tid; i < D1; i += 256) { s_b1[i] = b1[i]; s_b2[i] = b2[i]; }
    for (int i = tid; i < D1 * D1; i += 256) s_w2[i] = w2[i];
    for (int i = tid; i < NM * D1 * NA; i += 256) s_hw[i] = head_w[i];
    for (int i = tid; i < NM * NA; i += 256) s_hb[i] = head_b[i];

    int grp = tid >> 6, lane = tid & 63;
    int g = blockIdx.x * 4 + grp;
    if (lane < HC) {
        float cc = g_cnt[g];
        s_p[grp][lane] = g_pooled[g * HC + lane] / fmaxf(cc, 1.0f);
    }
    __syncthreads();
    {
        float a = s_b1[lane];
#pragma unroll
        for (int c = 0; c < HC; c++) a = fmaf(s_p[grp][c], s_w1[c * D1 + lane], a);
        s_g1[grp][lane] = a > 0.f ? a : expm1f(a);
    }
    __syncthreads();
    {
        float a = s_b2[lane];
#pragma unroll
        for (int d = 0; d < D1; d++) a = fmaf(s_g1[grp][d], s_w2[d * D1 + lane], a);
        s_g2[grp][lane] = a > 0.f ? a : expm1f(a);
    }
    __syncthreads();
    for (int idx = lane; idx < NM * NA; idx += 64) {
        int m = idx >> 3, a = idx & 7;
        float v = s_hb[idx];
#pragma unroll
        for (int d = 0; d < D1; d++)
            v = fmaf(s_g2[grp][d], s_hw[m * (D1 * NA) + d * NA + a], v);
        out[(size_t)g * (NM * NA) + idx] = v;
    }
}

extern "C" void kernel_launch(void* const* d_in, const int* in_sizes, int n_in,
                              void* d_out, int out_size, void* d_ws, size_t ws_size,
                              hipStream_t stream) {
    const float* x      = (const float*)d_in[0];
    const int*   ei     = (const int*)d_in[1];
    const int*   batch  = (const int*)d_in[2];
    const float* conv_w = (const float*)d_in[3];
    const float* conv_b = (const float*)d_in[4];
    const float* w1     = (const float*)d_in[5];
    const float* b1     = (const float*)d_in[6];
    const float* w2     = (const float*)d_in[7];
    const float* b2     = (const float*)d_in[8];
    const float* head_w = (const float*)d_in[9];
    const float* head_b = (const float*)d_in[10];
    float* out = (float*)d_out;

    k_zero<<<NBLK, 256, 0, stream>>>();
    k_bin<<<NBBLK, 1024, 0, stream>>>(ei);
    k_dinv<<<NBLK, 256, 0, stream>>>();
    k_xw<<<NN / 64, 256, 0, stream>>>(x, conv_w);
    k_agg<<<NBIN, 256, 0, stream>>>(conv_b, batch);
    k_mlp<<<NG / 4, 256, 0, stream>>>(w1, b1, w2, b2, head_w, head_b, out);
}